// Round 24
// baseline (168.416 us; speedup 1.0000x reference)
//
#include <hip/hip_runtime.h>
#include <hip/hip_bf16.h>
#include <math.h>

#define N_ROWS 65536
#define PSI    1024
#define DDIM   256

typedef _Float16       half8 __attribute__((ext_vector_type(8)));
typedef _Float16       half4 __attribute__((ext_vector_type(4)));
typedef float          f32x4 __attribute__((ext_vector_type(4)));
typedef int            i32x4 __attribute__((ext_vector_type(4)));

#define LOG2E 1.4426950408889634f
#define QSCALE 16.0f          // i8 quant: x8 = round(16x); |x|<5.5sigma -> no clip
#define INV128 0.0078125f     // 2 / (QSCALE^2)

// Raw-instruction transcendentals (~1-2 ulp, negligible vs 3.8e-6 f16 floor).
#if __has_builtin(__builtin_amdgcn_sqrtf)
#define FSQRT(x) __builtin_amdgcn_sqrtf(x)
#else
#define FSQRT(x) sqrtf(x)
#endif
#if __has_builtin(__builtin_amdgcn_exp2f)
#define FEXP2(x) __builtin_amdgcn_exp2f(x)
#else
#define FEXP2(x) exp2f(x)
#endif
#if __has_builtin(__builtin_amdgcn_rcpf)
#define FRCP(x) __builtin_amdgcn_rcpf(x)
#else
#define FRCP(x) (1.0f / (x))
#endif

// ---------- async global->LDS, 16B per lane ----------
__device__ __forceinline__ void gload16(const void* g, void* l) {
    __builtin_amdgcn_global_load_lds(
        (const __attribute__((address_space(1))) unsigned int*)g,
        (__attribute__((address_space(3))) unsigned int*)l, 16, 0, 0);
}

// ---------- fused convert (X,S) -> f16 + i8 + row norms + gsum init --------
// Plain cached loads (NT path measured slower on both loads and stores).
__global__ __launch_bounds__(256) void k_convert_all(
    const float* __restrict__ X, const float* __restrict__ S,
    _Float16* __restrict__ Xh, _Float16* __restrict__ Sh,
    char* __restrict__ Xi8, char* __restrict__ Si8,
    float* __restrict__ x2, float* __restrict__ s2,
    float* __restrict__ gsum)
{
    const int wib  = threadIdx.x >> 6;
    const int lane = threadIdx.x & 63;
    for (int u = blockIdx.x; u < 16640; u += 2048) {
        const float* in; _Float16* outh; char* outi; float* nrm; int row;
        if (u < 16384) { in = X; outh = Xh; outi = Xi8; nrm = x2; row = u * 4 + wib; }
        else { in = S; outh = Sh; outi = Si8; nrm = s2; row = (u - 16384) * 4 + wib; }
        const f32x4 v = *(const f32x4*)&in[(size_t)row * DDIM + lane * 4];
        float s = v[0] * v[0] + v[1] * v[1] + v[2] * v[2] + v[3] * v[3];
        #pragma unroll
        for (int o = 32; o > 0; o >>= 1) s += __shfl_down(s, o);
        if (lane == 0) nrm[row] = s;
        half4 h;
        h[0] = (_Float16)v[0]; h[1] = (_Float16)v[1];
        h[2] = (_Float16)v[2]; h[3] = (_Float16)v[3];
        *(half4*)&outh[(size_t)row * DDIM + lane * 4] = h;
        char4 q;
        #pragma unroll
        for (int i = 0; i < 4; ++i) {
            float t = fminf(fmaxf(v[i] * QSCALE, -127.0f), 127.0f);
            ((char*)&q)[i] = (char)__float2int_rn(t);
        }
        *(char4*)&outi[(size_t)row * DDIM + lane * 4] = q;
    }
    if (blockIdx.x == 0) {                    // re-init every call (graph replay)
        for (int i = threadIdx.x; i < PSI; i += 256) gsum[i] = 0.0f;
    }
}

// ---------- PASS 1: i8 MFMA, 256x256 tile, K=256 in two 128B halves --------
// Sums tolerate quantization (verified: absmax unchanged vs f16 pass-1).
// mfma_i32_16x16x64_i8: 2x f16 MFMA rate, half the staging bytes.
__global__ __launch_bounds__(512, 2) void k_gemm_sum_i8(
    const char* __restrict__ Xi8, const char* __restrict__ Si8,
    const float* __restrict__ x2, const float* __restrict__ s2,
    const float* __restrict__ w, float* __restrict__ gsum)
{
    __shared__ __align__(16) char As[2][256 * 128];   // 2 x 32 KB
    __shared__ __align__(16) char Bs[2][256 * 128];   // 2 x 32 KB

    const int tid = threadIdx.x;
    const int wv  = tid >> 6;       // 0..7
    const int wr  = wv >> 2;        // M half (128 rows)
    const int wc  = wv & 3;         // N quarter (64 cols)
    const int l15 = tid & 15;
    const int l4  = (tid & 63) >> 4;

    // XCD swizzle (nwg=1024 divisible by 8 -> bijective)
    const int fid  = blockIdx.x;
    const int wgid = (fid & 7) * 128 + (fid >> 3);
    const int rowb = wgid >> 2;          // 0..255
    const int row0 = rowb * 256;
    const int col0 = (wgid & 3) * 256;

    i32x4 acc[8][4];
    #pragma unroll
    for (int i = 0; i < 8; ++i)
        #pragma unroll
        for (int j = 0; j < 4; ++j) acc[i][j] = (i32x4){0, 0, 0, 0};

    const int grow = tid >> 3;           // 0..63
    const int gch  = (tid & 7) ^ (grow & 7);
    const char* gA = Xi8 + (size_t)(row0 + grow) * DDIM + gch * 16;
    const char* gB = Si8 + (size_t)(col0 + grow) * DDIM + gch * 16;

    auto stageA = [&](int h, int buf) {      // h = K-half (0,1), 128 B each
        #pragma unroll
        for (int rg = 0; rg < 4; ++rg)
            gload16(gA + (size_t)(rg * 64) * DDIM + h * 128,
                    &As[buf][rg * 8192 + wv * 1024]);
    };
    auto stageB = [&](int h, int buf) {
        #pragma unroll
        for (int rg = 0; rg < 4; ++rg)
            gload16(gB + (size_t)(rg * 64) * DDIM + h * 128,
                    &Bs[buf][rg * 8192 + wv * 1024]);
    };

    auto compute = [&](int buf) {
        #pragma unroll
        for (int tt = 0; tt < 2; ++tt) {     // 2 K-steps of 64 per half
            const int slot = (l4 + 4 * tt) ^ (l15 & 7);
            i32x4 af[8], bf[4];
            #pragma unroll
            for (int f = 0; f < 8; ++f)
                af[f] = *(const i32x4*)&As[buf][(wr * 128 + f * 16 + l15) * 128 + slot * 16];
            #pragma unroll
            for (int f = 0; f < 4; ++f)
                bf[f] = *(const i32x4*)&Bs[buf][(wc * 64 + f * 16 + l15) * 128 + slot * 16];
            __builtin_amdgcn_s_setprio(1);
            #pragma unroll
            for (int fm = 0; fm < 8; ++fm)
                #pragma unroll
                for (int fn = 0; fn < 4; ++fn)
                    acc[fm][fn] = __builtin_amdgcn_mfma_i32_16x16x64_i8(
                        af[fm], bf[fn], acc[fm][fn], 0, 0, 0);
            __builtin_amdgcn_s_setprio(0);
        }
    };

    stageA(0, 0); stageB(0, 0);
    __syncthreads();
    stageA(1, 1); stageB(1, 1);
    compute(0);
    __syncthreads();
    compute(1);
    __syncthreads();

    // ---- epilogue: column sums of u ----
    float4 x2r[8];
    #pragma unroll
    for (int fm = 0; fm < 8; ++fm)
        x2r[fm] = *(const float4*)&x2[row0 + wr * 128 + fm * 16 + l4 * 4];

    float* s_sm = (float*)&As[0][0];
    if (tid < 256) s_sm[tid] = 0.0f;
    __syncthreads();
    #pragma unroll
    for (int fn = 0; fn < 4; ++fn) {
        const int cl = wc * 64 + fn * 16 + l15;
        const int c  = col0 + cl;
        const float s2c = s2[c], ww2 = w[c] * LOG2E;
        float s = 0.0f;
        #pragma unroll
        for (int fm = 0; fm < 8; ++fm) {
            const float* xr = (const float*)&x2r[fm];
            #pragma unroll
            for (int j = 0; j < 4; ++j) {
                float d2 = xr[j] + s2c - (float)acc[fm][fn][j] * INV128;
                s += FEXP2(-FSQRT(fmaxf(d2, 0.0f)) * ww2);
            }
        }
        s += __shfl_xor(s, 16);
        s += __shfl_xor(s, 32);
        if (l4 == 0) atomicAdd(&s_sm[cl], s);   // 2 waves (wr) contend
    }
    __syncthreads();
    if (tid < 256) atomicAdd(&gsum[col0 + tid], s_sm[tid]);
}

// ---------- PASS 2: f16 MFMA, 128x128 tile, BK=32 dbuf, 32KB LDS -----------
// 4 blocks/CU (launch_bounds(256,4); ~100 VGPR fits the 128 cap -- R10
// proved no spill) to overlap the plain-store bursts across more resident
// blocks. LDS swizzle chunk ^= (row>>1)&3 both-sides (R10-proven geometry).
// out = u * rcp(gsum[c]), plain cached stores (64B-line coalesced).
__global__ __launch_bounds__(256, 4) void k_gemm_out(
    const _Float16* __restrict__ Xh, const _Float16* __restrict__ Sh,
    const float* __restrict__ x2, const float* __restrict__ s2,
    const float* __restrict__ w,
    const float* __restrict__ gsum, float* __restrict__ out)
{
    __shared__ _Float16 As[2][128 * 32];   // 2 x 8 KB
    __shared__ _Float16 Bs[2][128 * 32];   // 2 x 8 KB

    const int tid  = threadIdx.x;
    const int wv   = tid >> 6;
    const int wr   = wv >> 1;       // wave row half (0..1)
    const int wc   = wv & 1;        // wave col half (0..1)
    const int l15  = tid & 15;
    const int l4   = (tid & 63) >> 4;

    // XCD swizzle (nwg=4096 divisible by 8 -> bijective)
    const int fid   = blockIdx.x;
    const int wgid  = (fid & 7) * 512 + (fid >> 3);
    const int rowb  = wgid >> 3;            // 0..511
    const int row0  = rowb * 128;
    const int col0  = (wgid & 7) * 128;

    f32x4 acc[4][4];
    #pragma unroll
    for (int i = 0; i < 4; ++i)
        #pragma unroll
        for (int j = 0; j < 4; ++j) acc[i][j] = (f32x4){0.f, 0.f, 0.f, 0.f};

    // staging: thread covers rows rg*64 + (tid>>2), chunk tid&3 (16B chunks
    // of a 64B row). Pre-swizzled global k-chunk = (tid&3) ^ ((srow>>1)&3).
    const int srow = tid >> 2;              // 0..63
    const int skq  = ((tid & 3) ^ ((srow >> 1) & 3)) * 8;
    const _Float16* gAp = Xh + (size_t)(row0 + srow) * DDIM + skq;
    const _Float16* gBp = Sh + (size_t)(col0 + srow) * DDIM + skq;

    auto stage = [&](int k0, int b) {
        _Float16* Ab = &As[b][wv * 512];
        _Float16* Bb = &Bs[b][wv * 512];
        #pragma unroll
        for (int rg = 0; rg < 2; ++rg)
            gload16(gAp + (size_t)(rg * 64) * DDIM + k0, Ab + rg * 2048);
        #pragma unroll
        for (int rg = 0; rg < 2; ++rg)
            gload16(gBp + (size_t)(rg * 64) * DDIM + k0, Bb + rg * 2048);
    };

    auto compute = [&](int t) {
        const int b = t & 1;
        half8 af[4], bf[4];
        #pragma unroll
        for (int f = 0; f < 4; ++f) {
            const int ra = wr * 64 + f * 16 + l15;
            const int rb = wc * 64 + f * 16 + l15;
            const int ha = (ra * 32 + l4 * 8) ^ (((ra >> 1) & 3) << 3);
            const int hb = (rb * 32 + l4 * 8) ^ (((rb >> 1) & 3) << 3);
            af[f] = *(const half8*)&As[b][ha];
            bf[f] = *(const half8*)&Bs[b][hb];
        }
        #pragma unroll
        for (int fm = 0; fm < 4; ++fm)
            #pragma unroll
            for (int fn = 0; fn < 4; ++fn)
                acc[fm][fn] = __builtin_amdgcn_mfma_f32_16x16x32_f16(
                    af[fm], bf[fn], acc[fm][fn], 0, 0, 0);
    };

    stage(0, 0);
    __syncthreads();
    #pragma unroll
    for (int t = 0; t < 8; ++t) {           // K = 8 x 32
        if (t < 7) stage((t + 1) * 32, (t + 1) & 1);
        compute(t);
        if (t < 7) __syncthreads();
    }

    float4 x2r[4];
    #pragma unroll
    for (int fm = 0; fm < 4; ++fm)
        x2r[fm] = *(const float4*)&x2[row0 + wr * 64 + fm * 16 + l4 * 4];

    #pragma unroll
    for (int fn = 0; fn < 4; ++fn) {
        const int c = col0 + wc * 64 + fn * 16 + l15;
        const float s2c = s2[c], ww2 = w[c] * LOG2E;
        const float rsc = FRCP(gsum[c]);
        #pragma unroll
        for (int fm = 0; fm < 4; ++fm) {
            const float* xr = (const float*)&x2r[fm];
            const int rbase = row0 + wr * 64 + fm * 16 + l4 * 4;
            #pragma unroll
            for (int j = 0; j < 4; ++j) {
                float d2 = xr[j] + s2c - 2.0f * acc[fm][fn][j];
                float u  = FEXP2(-FSQRT(fmaxf(d2, 0.0f)) * ww2) * rsc;
                out[(size_t)(rbase + j) * PSI + c] = u;   // plain cached store
            }
        }
    }
}

extern "C" void kernel_launch(void* const* d_in, const int* in_sizes, int n_in,
                              void* d_out, int out_size, void* d_ws, size_t ws_size,
                              hipStream_t stream) {
    const float* X = (const float*)d_in[0];
    const float* S = (const float*)d_in[1];
    const float* w = (const float*)d_in[2];
    float* out = (float*)d_out;

    char* ws = (char*)d_ws;
    _Float16* Xh   = (_Float16*)(ws);                  // 33,554,432 B
    _Float16* Sh   = (_Float16*)(ws + 33554432);       //    524,288 B
    float*    x2   = (float*)   (ws + 34078720);       //    262,144 B
    float*    s2   = (float*)   (ws + 34340864);       //      4,096 B
    float*    gsum = (float*)   (ws + 34344960);       //      4,096 B
    char*     Xi8  = (char*)    (ws + 34349056);       // 16,777,216 B
    char*     Si8  = (char*)    (ws + 51126272);       //    262,144 B

    k_convert_all<<<dim3(2048), dim3(256), 0, stream>>>(
        X, S, Xh, Sh, Xi8, Si8, x2, s2, gsum);
    k_gemm_sum_i8<<<dim3(1024), dim3(512), 0, stream>>>(
        Xi8, Si8, x2, s2, w, gsum);
    k_gemm_out<<<dim3(4096), dim3(256), 0, stream>>>(
        Xh, Sh, x2, s2, w, gsum, out);
}

// Round 25
// 139.265 us; speedup vs baseline: 1.2093x; 1.2093x over previous
//
#include <hip/hip_runtime.h>
#include <hip/hip_bf16.h>
#include <math.h>

#define N_ROWS 65536
#define PSI    1024
#define DDIM   256

typedef _Float16       half8 __attribute__((ext_vector_type(8)));
typedef _Float16       half4 __attribute__((ext_vector_type(4)));
typedef float          f32x4 __attribute__((ext_vector_type(4)));
typedef int            i32x4 __attribute__((ext_vector_type(4)));

#define LOG2E 1.4426950408889634f
#define QSCALE 16.0f          // i8 quant: x8 = round(16x); |x|<5.5sigma -> no clip
#define INV128 0.0078125f     // 2 / (QSCALE^2)

// Raw-instruction transcendentals (~1-2 ulp, negligible vs 3.8e-6 f16 floor).
#if __has_builtin(__builtin_amdgcn_sqrtf)
#define FSQRT(x) __builtin_amdgcn_sqrtf(x)
#else
#define FSQRT(x) sqrtf(x)
#endif
#if __has_builtin(__builtin_amdgcn_exp2f)
#define FEXP2(x) __builtin_amdgcn_exp2f(x)
#else
#define FEXP2(x) exp2f(x)
#endif
#if __has_builtin(__builtin_amdgcn_rcpf)
#define FRCP(x) __builtin_amdgcn_rcpf(x)
#else
#define FRCP(x) (1.0f / (x))
#endif

// ---------- async global->LDS, 16B per lane ----------
__device__ __forceinline__ void gload16(const void* g, void* l) {
    __builtin_amdgcn_global_load_lds(
        (const __attribute__((address_space(1))) unsigned int*)g,
        (__attribute__((address_space(3))) unsigned int*)l, 16, 0, 0);
}

// ---------- fused convert (X,S) -> f16 + i8 + row norms + gsum init --------
// (R23 verbatim: NT source loads -- the R24 plain-load variant was part of a
// bundled regression; NT loads are the proven config here.)
__global__ __launch_bounds__(256) void k_convert_all(
    const float* __restrict__ X, const float* __restrict__ S,
    _Float16* __restrict__ Xh, _Float16* __restrict__ Sh,
    char* __restrict__ Xi8, char* __restrict__ Si8,
    float* __restrict__ x2, float* __restrict__ s2,
    float* __restrict__ gsum)
{
    const int wib  = threadIdx.x >> 6;
    const int lane = threadIdx.x & 63;
    for (int u = blockIdx.x; u < 16640; u += 2048) {
        const float* in; _Float16* outh; char* outi; float* nrm; int row;
        if (u < 16384) { in = X; outh = Xh; outi = Xi8; nrm = x2; row = u * 4 + wib; }
        else { in = S; outh = Sh; outi = Si8; nrm = s2; row = (u - 16384) * 4 + wib; }
        const f32x4 v = __builtin_nontemporal_load(
            (const f32x4*)&in[(size_t)row * DDIM + lane * 4]);
        float s = v[0] * v[0] + v[1] * v[1] + v[2] * v[2] + v[3] * v[3];
        #pragma unroll
        for (int o = 32; o > 0; o >>= 1) s += __shfl_down(s, o);
        if (lane == 0) nrm[row] = s;
        half4 h;
        h[0] = (_Float16)v[0]; h[1] = (_Float16)v[1];
        h[2] = (_Float16)v[2]; h[3] = (_Float16)v[3];
        *(half4*)&outh[(size_t)row * DDIM + lane * 4] = h;
        char4 q;
        #pragma unroll
        for (int i = 0; i < 4; ++i) {
            float t = fminf(fmaxf(v[i] * QSCALE, -127.0f), 127.0f);
            ((char*)&q)[i] = (char)__float2int_rn(t);
        }
        *(char4*)&outi[(size_t)row * DDIM + lane * 4] = q;
    }
    if (blockIdx.x == 0) {                    // re-init every call (graph replay)
        for (int i = threadIdx.x; i < PSI; i += 256) gsum[i] = 0.0f;
    }
}

// ---------- PASS 1: i8 MFMA, 256x256 tile, K=256 in two 128B halves --------
// (R23 verbatim.) Sums tolerate quantization (verified: absmax unchanged).
__global__ __launch_bounds__(512, 2) void k_gemm_sum_i8(
    const char* __restrict__ Xi8, const char* __restrict__ Si8,
    const float* __restrict__ x2, const float* __restrict__ s2,
    const float* __restrict__ w, float* __restrict__ gsum)
{
    __shared__ __align__(16) char As[2][256 * 128];   // 2 x 32 KB
    __shared__ __align__(16) char Bs[2][256 * 128];   // 2 x 32 KB

    const int tid = threadIdx.x;
    const int wv  = tid >> 6;       // 0..7
    const int wr  = wv >> 2;        // M half (128 rows)
    const int wc  = wv & 3;         // N quarter (64 cols)
    const int l15 = tid & 15;
    const int l4  = (tid & 63) >> 4;

    // XCD swizzle (nwg=1024 divisible by 8 -> bijective)
    const int fid  = blockIdx.x;
    const int wgid = (fid & 7) * 128 + (fid >> 3);
    const int rowb = wgid >> 2;          // 0..255
    const int row0 = rowb * 256;
    const int col0 = (wgid & 3) * 256;

    i32x4 acc[8][4];
    #pragma unroll
    for (int i = 0; i < 8; ++i)
        #pragma unroll
        for (int j = 0; j < 4; ++j) acc[i][j] = (i32x4){0, 0, 0, 0};

    const int grow = tid >> 3;           // 0..63
    const int gch  = (tid & 7) ^ (grow & 7);
    const char* gA = Xi8 + (size_t)(row0 + grow) * DDIM + gch * 16;
    const char* gB = Si8 + (size_t)(col0 + grow) * DDIM + gch * 16;

    auto stageA = [&](int h, int buf) {      // h = K-half (0,1), 128 B each
        #pragma unroll
        for (int rg = 0; rg < 4; ++rg)
            gload16(gA + (size_t)(rg * 64) * DDIM + h * 128,
                    &As[buf][rg * 8192 + wv * 1024]);
    };
    auto stageB = [&](int h, int buf) {
        #pragma unroll
        for (int rg = 0; rg < 4; ++rg)
            gload16(gB + (size_t)(rg * 64) * DDIM + h * 128,
                    &Bs[buf][rg * 8192 + wv * 1024]);
    };

    auto compute = [&](int buf) {
        #pragma unroll
        for (int tt = 0; tt < 2; ++tt) {     // 2 K-steps of 64 per half
            const int slot = (l4 + 4 * tt) ^ (l15 & 7);
            i32x4 af[8], bf[4];
            #pragma unroll
            for (int f = 0; f < 8; ++f)
                af[f] = *(const i32x4*)&As[buf][(wr * 128 + f * 16 + l15) * 128 + slot * 16];
            #pragma unroll
            for (int f = 0; f < 4; ++f)
                bf[f] = *(const i32x4*)&Bs[buf][(wc * 64 + f * 16 + l15) * 128 + slot * 16];
            __builtin_amdgcn_s_setprio(1);
            #pragma unroll
            for (int fm = 0; fm < 8; ++fm)
                #pragma unroll
                for (int fn = 0; fn < 4; ++fn)
                    acc[fm][fn] = __builtin_amdgcn_mfma_i32_16x16x64_i8(
                        af[fm], bf[fn], acc[fm][fn], 0, 0, 0);
            __builtin_amdgcn_s_setprio(0);
        }
    };

    stageA(0, 0); stageB(0, 0);
    __syncthreads();
    stageA(1, 1); stageB(1, 1);
    compute(0);
    __syncthreads();
    compute(1);
    __syncthreads();

    // ---- epilogue: column sums of u ----
    float4 x2r[8];
    #pragma unroll
    for (int fm = 0; fm < 8; ++fm)
        x2r[fm] = *(const float4*)&x2[row0 + wr * 128 + fm * 16 + l4 * 4];

    float* s_sm = (float*)&As[0][0];
    if (tid < 256) s_sm[tid] = 0.0f;
    __syncthreads();
    #pragma unroll
    for (int fn = 0; fn < 4; ++fn) {
        const int cl = wc * 64 + fn * 16 + l15;
        const int c  = col0 + cl;
        const float s2c = s2[c], ww2 = w[c] * LOG2E;
        float s = 0.0f;
        #pragma unroll
        for (int fm = 0; fm < 8; ++fm) {
            const float* xr = (const float*)&x2r[fm];
            #pragma unroll
            for (int j = 0; j < 4; ++j) {
                float d2 = xr[j] + s2c - (float)acc[fm][fn][j] * INV128;
                s += FEXP2(-FSQRT(fmaxf(d2, 0.0f)) * ww2);
            }
        }
        s += __shfl_xor(s, 16);
        s += __shfl_xor(s, 32);
        if (l4 == 0) atomicAdd(&s_sm[cl], s);   // 2 waves (wr) contend
    }
    __syncthreads();
    if (tid < 256) atomicAdd(&gsum[col0 + tid], s_sm[tid]);
}

// ---------- PASS 2: f16 MFMA, 128x128 tile, BK=64 2-phase dbuf (R23) -------
// SWAPPED operands mfma(bf,af) in this pass: lane holds row=l15 (per fm)
// and 4 CONSECUTIVE cols (l4*4+j) -> f32x4 plain stores (16/thread vs 64
// scalar). Layout refcheck-verified in R18; retested here under plain
// cached stores where issue count is a larger share of the store path.
__global__ __launch_bounds__(256) void k_gemm_out(
    const _Float16* __restrict__ Xh, const _Float16* __restrict__ Sh,
    const float* __restrict__ x2, const float* __restrict__ s2,
    const float* __restrict__ w,
    const float* __restrict__ gsum, float* __restrict__ out)
{
    __shared__ _Float16 As[2][128 * 64];   // 2 x 16 KB
    __shared__ _Float16 Bs[2][128 * 64];   // 2 x 16 KB

    const int tid  = threadIdx.x;
    const int wv   = tid >> 6;
    const int wr   = wv >> 1;       // wave row half (0..1)
    const int wc   = wv & 1;        // wave col half (0..1)
    const int l15  = tid & 15;
    const int l4   = (tid & 63) >> 4;

    // XCD swizzle (nwg=4096 divisible by 8 -> bijective)
    const int fid   = blockIdx.x;
    const int wgid  = (fid & 7) * 512 + (fid >> 3);
    const int rowb  = wgid >> 3;            // 0..511
    const int row0  = rowb * 128;
    const int col0  = (wgid & 7) * 128;

    f32x4 acc[4][4];
    #pragma unroll
    for (int i = 0; i < 4; ++i)
        #pragma unroll
        for (int j = 0; j < 4; ++j) acc[i][j] = (f32x4){0.f, 0.f, 0.f, 0.f};

    const int srow = tid >> 3;
    const int skq  = ((tid & 7) ^ (srow & 7)) * 8;
    const _Float16* gAp = Xh + (size_t)(row0 + srow) * DDIM + skq;
    const _Float16* gBp = Sh + (size_t)(col0 + srow) * DDIM + skq;

    auto stage = [&](int k0, int b) {
        _Float16* Ab = &As[b][wv * 512];
        _Float16* Bb = &Bs[b][wv * 512];
        #pragma unroll
        for (int rg = 0; rg < 4; ++rg)
            gload16(gAp + (size_t)(rg * 32) * DDIM + k0, Ab + rg * 2048);
        #pragma unroll
        for (int rg = 0; rg < 4; ++rg)
            gload16(gBp + (size_t)(rg * 32) * DDIM + k0, Bb + rg * 2048);
    };

    auto compute = [&](int b) {
        #pragma unroll
        for (int kk = 0; kk < 2; ++kk) {
            half8 af[4], bf[4];
            #pragma unroll
            for (int f = 0; f < 4; ++f) {
                const int swz = (l15 & 7) << 3;               // halfs
                const int ha = ((wr * 64 + f * 16 + l15) * 64 + kk * 32 + l4 * 8) ^ swz;
                const int hb = ((wc * 64 + f * 16 + l15) * 64 + kk * 32 + l4 * 8) ^ swz;
                af[f] = *(const half8*)&As[b][ha];
                bf[f] = *(const half8*)&Bs[b][hb];
            }
            #pragma unroll
            for (int fm = 0; fm < 4; ++fm)
                #pragma unroll
                for (int fn = 0; fn < 4; ++fn)
                    acc[fm][fn] = __builtin_amdgcn_mfma_f32_16x16x32_f16(
                        bf[fn], af[fm], acc[fm][fn], 0, 0, 0);   // swapped
        }
    };

    stage(0, 0);
    __syncthreads();
    #pragma unroll
    for (int t = 0; t < 4; ++t) {           // K = 4 x 64
        if (t < 3) stage((t + 1) * 64, (t + 1) & 1);
        compute(t & 1);
        if (t < 3) __syncthreads();
    }

    // swapped layout: row = l15 (per fm), cols = l4*4+j (4 consecutive)
    float x2s[4];
    #pragma unroll
    for (int fm = 0; fm < 4; ++fm)
        x2s[fm] = x2[row0 + wr * 64 + fm * 16 + l15];
    #pragma unroll
    for (int fn = 0; fn < 4; ++fn) {
        const int cb = col0 + wc * 64 + fn * 16 + l4 * 4;
        const f32x4 s2v = *(const f32x4*)&s2[cb];
        const f32x4 wv4 = *(const f32x4*)&w[cb];
        const f32x4 gv  = *(const f32x4*)&gsum[cb];
        f32x4 w2v, rv;
        #pragma unroll
        for (int j = 0; j < 4; ++j) {
            w2v[j] = wv4[j] * LOG2E;
            rv[j]  = FRCP(gv[j]);
        }
        #pragma unroll
        for (int fm = 0; fm < 4; ++fm) {
            const size_t r = (size_t)(row0 + wr * 64 + fm * 16 + l15);
            f32x4 o;
            #pragma unroll
            for (int j = 0; j < 4; ++j) {
                float d2 = x2s[fm] + s2v[j] - 2.0f * acc[fm][fn][j];
                o[j] = FEXP2(-FSQRT(fmaxf(d2, 0.0f)) * w2v[j]) * rv[j];
            }
            *(f32x4*)&out[r * PSI + cb] = o;   // plain cached f32x4 store
        }
    }
}

extern "C" void kernel_launch(void* const* d_in, const int* in_sizes, int n_in,
                              void* d_out, int out_size, void* d_ws, size_t ws_size,
                              hipStream_t stream) {
    const float* X = (const float*)d_in[0];
    const float* S = (const float*)d_in[1];
    const float* w = (const float*)d_in[2];
    float* out = (float*)d_out;

    char* ws = (char*)d_ws;
    _Float16* Xh   = (_Float16*)(ws);                  // 33,554,432 B
    _Float16* Sh   = (_Float16*)(ws + 33554432);       //    524,288 B
    float*    x2   = (float*)   (ws + 34078720);       //    262,144 B
    float*    s2   = (float*)   (ws + 34340864);       //      4,096 B
    float*    gsum = (float*)   (ws + 34344960);       //      4,096 B
    char*     Xi8  = (char*)    (ws + 34349056);       // 16,777,216 B
    char*     Si8  = (char*)    (ws + 51126272);       //    262,144 B

    k_convert_all<<<dim3(2048), dim3(256), 0, stream>>>(
        X, S, Xh, Sh, Xi8, Si8, x2, s2, gsum);
    k_gemm_sum_i8<<<dim3(1024), dim3(512), 0, stream>>>(
        Xi8, Si8, x2, s2, w, gsum);
    k_gemm_out<<<dim3(4096), dim3(256), 0, stream>>>(
        Xh, Sh, x2, s2, w, gsum, out);
}

// Round 26
// 132.459 us; speedup vs baseline: 1.2715x; 1.0514x over previous
//
#include <hip/hip_runtime.h>
#include <hip/hip_bf16.h>
#include <math.h>

#define N_ROWS 65536
#define PSI    1024
#define DDIM   256

typedef _Float16       half8 __attribute__((ext_vector_type(8)));
typedef _Float16       half4 __attribute__((ext_vector_type(4)));
typedef float          f32x4 __attribute__((ext_vector_type(4)));
typedef int            i32x4 __attribute__((ext_vector_type(4)));

#define LOG2E 1.4426950408889634f
#define QSCALE 16.0f          // i8 quant: x8 = round(16x); |x|<5.5sigma -> no clip
#define INV128 0.0078125f     // 2 / (QSCALE^2)

// Raw-instruction transcendentals (~1-2 ulp, negligible vs 3.8e-6 f16 floor).
#if __has_builtin(__builtin_amdgcn_sqrtf)
#define FSQRT(x) __builtin_amdgcn_sqrtf(x)
#else
#define FSQRT(x) sqrtf(x)
#endif
#if __has_builtin(__builtin_amdgcn_exp2f)
#define FEXP2(x) __builtin_amdgcn_exp2f(x)
#else
#define FEXP2(x) exp2f(x)
#endif
#if __has_builtin(__builtin_amdgcn_rcpf)
#define FRCP(x) __builtin_amdgcn_rcpf(x)
#else
#define FRCP(x) (1.0f / (x))
#endif

// ---------- async global->LDS, 16B per lane ----------
__device__ __forceinline__ void gload16(const void* g, void* l) {
    __builtin_amdgcn_global_load_lds(
        (const __attribute__((address_space(1))) unsigned int*)g,
        (__attribute__((address_space(3))) unsigned int*)l, 16, 0, 0);
}

// ---------- fused convert (X,S) -> f16 + i8 + row norms + gsum init --------
__global__ __launch_bounds__(256) void k_convert_all(
    const float* __restrict__ X, const float* __restrict__ S,
    _Float16* __restrict__ Xh, _Float16* __restrict__ Sh,
    char* __restrict__ Xi8, char* __restrict__ Si8,
    float* __restrict__ x2, float* __restrict__ s2,
    float* __restrict__ gsum)
{
    const int wib  = threadIdx.x >> 6;
    const int lane = threadIdx.x & 63;
    for (int u = blockIdx.x; u < 16640; u += 2048) {
        const float* in; _Float16* outh; char* outi; float* nrm; int row;
        if (u < 16384) { in = X; outh = Xh; outi = Xi8; nrm = x2; row = u * 4 + wib; }
        else { in = S; outh = Sh; outi = Si8; nrm = s2; row = (u - 16384) * 4 + wib; }
        const f32x4 v = __builtin_nontemporal_load(
            (const f32x4*)&in[(size_t)row * DDIM + lane * 4]);
        float s = v[0] * v[0] + v[1] * v[1] + v[2] * v[2] + v[3] * v[3];
        #pragma unroll
        for (int o = 32; o > 0; o >>= 1) s += __shfl_down(s, o);
        if (lane == 0) nrm[row] = s;
        half4 h;
        h[0] = (_Float16)v[0]; h[1] = (_Float16)v[1];
        h[2] = (_Float16)v[2]; h[3] = (_Float16)v[3];
        *(half4*)&outh[(size_t)row * DDIM + lane * 4] = h;
        char4 q;
        #pragma unroll
        for (int i = 0; i < 4; ++i) {
            float t = fminf(fmaxf(v[i] * QSCALE, -127.0f), 127.0f);
            ((char*)&q)[i] = (char)__float2int_rn(t);
        }
        *(char4*)&outi[(size_t)row * DDIM + lane * 4] = q;
    }
    if (blockIdx.x == 0) {                    // re-init every call (graph replay)
        for (int i = threadIdx.x; i < PSI; i += 256) gsum[i] = 0.0f;
    }
}

// ---------- PASS 1: i8 MFMA, 256x256 tile, K=256 in two 128B halves --------
// Sums tolerate quantization (verified: absmax unchanged vs f16 pass-1).
// mfma_i32_16x16x64_i8: 2x f16 MFMA rate, half the staging bytes.
__global__ __launch_bounds__(512, 2) void k_gemm_sum_i8(
    const char* __restrict__ Xi8, const char* __restrict__ Si8,
    const float* __restrict__ x2, const float* __restrict__ s2,
    const float* __restrict__ w, float* __restrict__ gsum)
{
    __shared__ __align__(16) char As[2][256 * 128];   // 2 x 32 KB
    __shared__ __align__(16) char Bs[2][256 * 128];   // 2 x 32 KB

    const int tid = threadIdx.x;
    const int wv  = tid >> 6;       // 0..7
    const int wr  = wv >> 2;        // M half (128 rows)
    const int wc  = wv & 3;         // N quarter (64 cols)
    const int l15 = tid & 15;
    const int l4  = (tid & 63) >> 4;

    // XCD swizzle (nwg=1024 divisible by 8 -> bijective)
    const int fid  = blockIdx.x;
    const int wgid = (fid & 7) * 128 + (fid >> 3);
    const int rowb = wgid >> 2;          // 0..255
    const int row0 = rowb * 256;
    const int col0 = (wgid & 3) * 256;

    i32x4 acc[8][4];
    #pragma unroll
    for (int i = 0; i < 8; ++i)
        #pragma unroll
        for (int j = 0; j < 4; ++j) acc[i][j] = (i32x4){0, 0, 0, 0};

    const int grow = tid >> 3;           // 0..63
    const int gch  = (tid & 7) ^ (grow & 7);
    const char* gA = Xi8 + (size_t)(row0 + grow) * DDIM + gch * 16;
    const char* gB = Si8 + (size_t)(col0 + grow) * DDIM + gch * 16;

    auto stageA = [&](int h, int buf) {      // h = K-half (0,1), 128 B each
        #pragma unroll
        for (int rg = 0; rg < 4; ++rg)
            gload16(gA + (size_t)(rg * 64) * DDIM + h * 128,
                    &As[buf][rg * 8192 + wv * 1024]);
    };
    auto stageB = [&](int h, int buf) {
        #pragma unroll
        for (int rg = 0; rg < 4; ++rg)
            gload16(gB + (size_t)(rg * 64) * DDIM + h * 128,
                    &Bs[buf][rg * 8192 + wv * 1024]);
    };

    auto compute = [&](int buf) {
        #pragma unroll
        for (int tt = 0; tt < 2; ++tt) {     // 2 K-steps of 64 per half
            const int slot = (l4 + 4 * tt) ^ (l15 & 7);
            i32x4 af[8], bf[4];
            #pragma unroll
            for (int f = 0; f < 8; ++f)
                af[f] = *(const i32x4*)&As[buf][(wr * 128 + f * 16 + l15) * 128 + slot * 16];
            #pragma unroll
            for (int f = 0; f < 4; ++f)
                bf[f] = *(const i32x4*)&Bs[buf][(wc * 64 + f * 16 + l15) * 128 + slot * 16];
            __builtin_amdgcn_s_setprio(1);
            #pragma unroll
            for (int fm = 0; fm < 8; ++fm)
                #pragma unroll
                for (int fn = 0; fn < 4; ++fn)
                    acc[fm][fn] = __builtin_amdgcn_mfma_i32_16x16x64_i8(
                        af[fm], bf[fn], acc[fm][fn], 0, 0, 0);
            __builtin_amdgcn_s_setprio(0);
        }
    };

    stageA(0, 0); stageB(0, 0);
    __syncthreads();
    stageA(1, 1); stageB(1, 1);
    compute(0);
    __syncthreads();
    compute(1);
    __syncthreads();

    // ---- epilogue: column sums of u ----
    float4 x2r[8];
    #pragma unroll
    for (int fm = 0; fm < 8; ++fm)
        x2r[fm] = *(const float4*)&x2[row0 + wr * 128 + fm * 16 + l4 * 4];

    float* s_sm = (float*)&As[0][0];
    if (tid < 256) s_sm[tid] = 0.0f;
    __syncthreads();
    #pragma unroll
    for (int fn = 0; fn < 4; ++fn) {
        const int cl = wc * 64 + fn * 16 + l15;
        const int c  = col0 + cl;
        const float s2c = s2[c], ww2 = w[c] * LOG2E;
        float s = 0.0f;
        #pragma unroll
        for (int fm = 0; fm < 8; ++fm) {
            const float* xr = (const float*)&x2r[fm];
            #pragma unroll
            for (int j = 0; j < 4; ++j) {
                float d2 = xr[j] + s2c - (float)acc[fm][fn][j] * INV128;
                s += FEXP2(-FSQRT(fmaxf(d2, 0.0f)) * ww2);
            }
        }
        s += __shfl_xor(s, 16);
        s += __shfl_xor(s, 32);
        if (l4 == 0) atomicAdd(&s_sm[cl], s);   // 2 waves (wr) contend
    }
    __syncthreads();
    if (tid < 256) atomicAdd(&gsum[col0 + tid], s_sm[tid]);
}

// ---------- PASS 2: f16 MFMA, 128x128 tile, BK=64 2-phase dbuf -------------
// Unswapped mfma(af,bf): lane layout col=l15 -> 16 lanes span 16 consecutive
// columns = coalesced 64B lines per quarter-wave (the swapped f32x4 variant
// scatters 16 rows -> regressed, R25). Plain cached stores (7 TB/s vs ~5 NT).
__global__ __launch_bounds__(256) void k_gemm_out(
    const _Float16* __restrict__ Xh, const _Float16* __restrict__ Sh,
    const float* __restrict__ x2, const float* __restrict__ s2,
    const float* __restrict__ w,
    const float* __restrict__ gsum, float* __restrict__ out)
{
    __shared__ _Float16 As[2][128 * 64];   // 2 x 16 KB
    __shared__ _Float16 Bs[2][128 * 64];   // 2 x 16 KB

    const int tid  = threadIdx.x;
    const int wv   = tid >> 6;
    const int wr   = wv >> 1;       // wave row half (0..1)
    const int wc   = wv & 1;        // wave col half (0..1)
    const int l15  = tid & 15;
    const int l4   = (tid & 63) >> 4;

    // XCD swizzle (nwg=4096 divisible by 8 -> bijective)
    const int fid   = blockIdx.x;
    const int wgid  = (fid & 7) * 512 + (fid >> 3);
    const int rowb  = wgid >> 3;            // 0..511
    const int row0  = rowb * 128;
    const int col0  = (wgid & 7) * 128;

    f32x4 acc[4][4];
    #pragma unroll
    for (int i = 0; i < 4; ++i)
        #pragma unroll
        for (int j = 0; j < 4; ++j) acc[i][j] = (f32x4){0.f, 0.f, 0.f, 0.f};

    const int srow = tid >> 3;
    const int skq  = ((tid & 7) ^ (srow & 7)) * 8;
    const _Float16* gAp = Xh + (size_t)(row0 + srow) * DDIM + skq;
    const _Float16* gBp = Sh + (size_t)(col0 + srow) * DDIM + skq;

    auto stage = [&](int k0, int b) {
        _Float16* Ab = &As[b][wv * 512];
        _Float16* Bb = &Bs[b][wv * 512];
        #pragma unroll
        for (int rg = 0; rg < 4; ++rg)
            gload16(gAp + (size_t)(rg * 32) * DDIM + k0, Ab + rg * 2048);
        #pragma unroll
        for (int rg = 0; rg < 4; ++rg)
            gload16(gBp + (size_t)(rg * 32) * DDIM + k0, Bb + rg * 2048);
    };

    auto compute = [&](int b) {
        #pragma unroll
        for (int kk = 0; kk < 2; ++kk) {
            half8 af[4], bf[4];
            #pragma unroll
            for (int f = 0; f < 4; ++f) {
                const int swz = (l15 & 7) << 3;               // halfs
                const int ha = ((wr * 64 + f * 16 + l15) * 64 + kk * 32 + l4 * 8) ^ swz;
                const int hb = ((wc * 64 + f * 16 + l15) * 64 + kk * 32 + l4 * 8) ^ swz;
                af[f] = *(const half8*)&As[b][ha];
                bf[f] = *(const half8*)&Bs[b][hb];
            }
            #pragma unroll
            for (int fm = 0; fm < 4; ++fm)
                #pragma unroll
                for (int fn = 0; fn < 4; ++fn)
                    acc[fm][fn] = __builtin_amdgcn_mfma_f32_16x16x32_f16(
                        af[fm], bf[fn], acc[fm][fn], 0, 0, 0);
        }
    };

    stage(0, 0);
    __syncthreads();
    #pragma unroll
    for (int t = 0; t < 4; ++t) {           // K = 4 x 64
        if (t < 3) stage((t + 1) * 64, (t + 1) & 1);
        compute(t & 1);
        if (t < 3) __syncthreads();
    }

    float4 x2r[4];
    #pragma unroll
    for (int fm = 0; fm < 4; ++fm)
        x2r[fm] = *(const float4*)&x2[row0 + wr * 64 + fm * 16 + l4 * 4];

    #pragma unroll
    for (int fn = 0; fn < 4; ++fn) {
        const int c = col0 + wc * 64 + fn * 16 + l15;
        const float s2c = s2[c], ww2 = w[c] * LOG2E;
        const float rsc = FRCP(gsum[c]);
        #pragma unroll
        for (int fm = 0; fm < 4; ++fm) {
            const float* xr = (const float*)&x2r[fm];
            const int rbase = row0 + wr * 64 + fm * 16 + l4 * 4;
            #pragma unroll
            for (int j = 0; j < 4; ++j) {
                float d2 = xr[j] + s2c - 2.0f * acc[fm][fn][j];
                float u  = FEXP2(-FSQRT(fmaxf(d2, 0.0f)) * ww2) * rsc;
                out[(size_t)(rbase + j) * PSI + c] = u;   // plain cached store
            }
        }
    }
}

extern "C" void kernel_launch(void* const* d_in, const int* in_sizes, int n_in,
                              void* d_out, int out_size, void* d_ws, size_t ws_size,
                              hipStream_t stream) {
    const float* X = (const float*)d_in[0];
    const float* S = (const float*)d_in[1];
    const float* w = (const float*)d_in[2];
    float* out = (float*)d_out;

    char* ws = (char*)d_ws;
    _Float16* Xh   = (_Float16*)(ws);                  // 33,554,432 B
    _Float16* Sh   = (_Float16*)(ws + 33554432);       //    524,288 B
    float*    x2   = (float*)   (ws + 34078720);       //    262,144 B
    float*    s2   = (float*)   (ws + 34340864);       //      4,096 B
    float*    gsum = (float*)   (ws + 34344960);       //      4,096 B
    char*     Xi8  = (char*)    (ws + 34349056);       // 16,777,216 B
    char*     Si8  = (char*)    (ws + 51126272);       //    262,144 B

    k_convert_all<<<dim3(2048), dim3(256), 0, stream>>>(
        X, S, Xh, Sh, Xi8, Si8, x2, s2, gsum);
    k_gemm_sum_i8<<<dim3(1024), dim3(512), 0, stream>>>(
        Xi8, Si8, x2, s2, w, gsum);
    k_gemm_out<<<dim3(4096), dim3(256), 0, stream>>>(
        Xh, Sh, x2, s2, w, gsum, out);
}